// Round 14
// baseline (137.279 us; speedup 1.0000x reference)
//
#include <hip/hip_runtime.h>
#include <hip/hip_bf16.h>

// Shapes: x[2,16,1024,512] f32, past_kv[2,16,64,64] f32, Wq/Wk/Wv[64,512], b*[64]
// Outputs (concat): out [2,16,1024,64] (group-normed), current_kv [2,16,1024,64,64]

constexpr int B  = 2;
constexpr int NH = 16;
constexpr int L  = 1024;
constexpr int E  = 512;
constexpr int D  = 64;
constexpr int M  = B * NH * L;     // 32768 rows
constexpr int NQKV = 192;
constexpr int SBLK = 8;            // positions per store block
constexpr int NSBLKS = M / SBLK;   // 4096
constexpr float EPS = 1e-5f;

using short8 = __attribute__((ext_vector_type(8))) short;
using f32x4  = __attribute__((ext_vector_type(4))) float;

// Native packed f32->bf16 (RTNE): compiles to v_cvt_pk_bf16_f32 (1 op / 2 floats)
__device__ __forceinline__ unsigned int cvt2(float lo, float hi) {
    __hip_bfloat162 p = __float22bfloat162_rn(make_float2(lo, hi));
    unsigned int u;
    __builtin_memcpy(&u, &p, 4);
    return u;
}
__device__ __forceinline__ unsigned short f2bf(float f) {
    __hip_bfloat16 b = __float2bfloat16(f);
    unsigned short u;
    __builtin_memcpy(&u, &b, 2);
    return u;
}
__device__ __forceinline__ float bf2f(unsigned short h) {
    union { unsigned int u; float f; } x; x.u = ((unsigned int)h) << 16;
    return x.f;
}

// ---------------------------------------------------------------------------
// Kernel 1: QKV projection via bf16 MFMA -> bf16 qkv. BM=64, XCD-swizzled.
// W converted f32->bf16 on the fly (packed cvt) during staging.
// ---------------------------------------------------------------------------
__global__ __launch_bounds__(512) void proj_mfma_kernel(
    const float* __restrict__ x,
    const float* __restrict__ Wq, const float* __restrict__ Wk,
    const float* __restrict__ Wv,
    const float* __restrict__ bq, const float* __restrict__ bk,
    const float* __restrict__ bv,
    unsigned short* __restrict__ qkvb)   // [M,192] bf16
{
    constexpr int BM = 64, BK = 64, LDP = 72;
    __shared__ unsigned short Xs[BM][LDP];
    __shared__ unsigned short Ws[NQKV][LDP];
    __shared__ float bias_s[NQKV];

    const int tid  = threadIdx.x;
    // XCD swizzle: 512 blocks = 8 XCDs x 64
    const int blk  = (blockIdx.x & 7) * 64 + (blockIdx.x >> 3);
    const int row0 = blk * BM;
    if (tid < NQKV)
        bias_s[tid] = (tid < 64) ? bq[tid] : (tid < 128) ? bk[tid - 64] : bv[tid - 128];

    const int wid  = tid >> 6;
    const int lane = tid & 63;
    const int wr   = wid >> 2;            // 0..1 row half (32 rows)
    const int wc   = wid & 3;             // 0..3 col block (48 cols)
    const int l15  = lane & 15;
    const int lk   = (lane >> 4) * 8;

    // Per-thread W staging targets (k-invariant)
    const float* wsrc[3];
    int wr8[3], wc8[3];
    #pragma unroll
    for (int j = 0; j < 3; ++j) {
        int c = tid + j * 512;            // chunk 0..1535
        int wrow = c >> 3;                // 0..191
        wsrc[j] = (wrow < 64) ? Wq : (wrow < 128) ? Wk : Wv;
        wr8[j]  = wrow & 63;
        wc8[j]  = (c & 7) * 8;
    }

    f32x4 acc[2][3] = {};

    for (int k0 = 0; k0 < E; k0 += BK) {
        float4 xa[2];
        #pragma unroll
        for (int j = 0; j < 2; ++j) {
            int f = tid + j * 512;
            xa[j] = *(const float4*)&x[(size_t)(row0 + (f >> 4)) * E + k0 + (f & 15) * 4];
        }
        float4 wa[3][2];
        #pragma unroll
        for (int j = 0; j < 3; ++j) {
            wa[j][0] = *(const float4*)&wsrc[j][(size_t)wr8[j] * E + k0 + wc8[j]];
            wa[j][1] = *(const float4*)&wsrc[j][(size_t)wr8[j] * E + k0 + wc8[j] + 4];
        }
        __syncthreads();   // previous tile fully consumed
        #pragma unroll
        for (int j = 0; j < 2; ++j) {
            int f = tid + j * 512;
            uint2 t;
            t.x = cvt2(xa[j].x, xa[j].y);
            t.y = cvt2(xa[j].z, xa[j].w);
            *(uint2*)&Xs[f >> 4][(f & 15) * 4] = t;
        }
        #pragma unroll
        for (int j = 0; j < 3; ++j) {
            int c = tid + j * 512;
            uint4 t;
            t.x = cvt2(wa[j][0].x, wa[j][0].y);
            t.y = cvt2(wa[j][0].z, wa[j][0].w);
            t.z = cvt2(wa[j][1].x, wa[j][1].y);
            t.w = cvt2(wa[j][1].z, wa[j][1].w);
            *(uint4*)&Ws[c >> 3][(c & 7) * 8] = t;
        }
        __syncthreads();

        #pragma unroll
        for (int kk = 0; kk < 2; ++kk) {
            short8 a[2], b[3];
            #pragma unroll
            for (int mi = 0; mi < 2; ++mi)
                a[mi] = *(const short8*)&Xs[wr * 32 + mi * 16 + l15][kk * 32 + lk];
            #pragma unroll
            for (int ni = 0; ni < 3; ++ni)
                b[ni] = *(const short8*)&Ws[wc * 48 + ni * 16 + l15][kk * 32 + lk];
            #pragma unroll
            for (int mi = 0; mi < 2; ++mi)
                #pragma unroll
                for (int ni = 0; ni < 3; ++ni)
                    acc[mi][ni] = __builtin_amdgcn_mfma_f32_16x16x32_bf16(
                        a[mi], b[ni], acc[mi][ni], 0, 0, 0);
        }
    }

    #pragma unroll
    for (int mi = 0; mi < 2; ++mi) {
        #pragma unroll
        for (int ni = 0; ni < 3; ++ni) {
            int col = wc * 48 + ni * 16 + l15;
            float bb = bias_s[col];
            #pragma unroll
            for (int j = 0; j < 4; ++j) {
                int row = wr * 32 + mi * 16 + (lane >> 4) * 4 + j;
                qkvb[(size_t)(row0 + row) * NQKV + col] = f2bf(acc[mi][ni][j] + bb);
            }
        }
    }
}

// ---------------------------------------------------------------------------
// Kernel 2: store + out. 4096 blocks x 256 threads, 3 KB LDS, XCD-swizzled.
// (byte-identical logic to R11/R12 — best measured)
// ---------------------------------------------------------------------------
__global__ __launch_bounds__(256) void store_out_kernel(
    const unsigned short* __restrict__ qkvb,  // [M,192] bf16
    const float* __restrict__ past_kv,        // [B*NH,64,64] f32
    float* __restrict__ out,                  // [M,64] (pre-norm)
    float* __restrict__ ckv,                  // [M,4096]
    float* __restrict__ partials)             // [NSBLKS,2]
{
    __shared__ unsigned short qkv_s[SBLK * NQKV];   // 3 KB
    __shared__ float qk_s[SBLK];
    __shared__ float red[8];

    const int blk  = (blockIdx.x & 7) * 512 + (blockIdx.x >> 3);
    const int bn   = blk >> 7;             // 128 blocks per (b,n)
    const int pos0 = (blk & 127) * SBLK;
    const int h    = bn & (NH - 1);
    const int tid  = threadIdx.x;
    const float decay = 1.0f - exp2f(-5.0f - (float)h);

    const unsigned short* qrow = qkvb + (size_t)(bn * L + pos0) * NQKV;
    if (tid < 192) ((uint4*)qkv_s)[tid] = ((const uint4*)qrow)[tid];

    const float* pkv = past_kv + (size_t)bn * 4096;
    float4 p4[4];
    #pragma unroll
    for (int j = 0; j < 4; ++j)
        p4[j] = *(const float4*)&pkv[(tid + j * 256) * 4];
    __syncthreads();

    if (tid < 64) {
        int pos = tid >> 3, c = tid & 7;
        const unsigned short* qp = &qkv_s[pos * NQKV];
        float p = 0.0f;
        #pragma unroll
        for (int j = 0; j < 8; ++j)
            p = fmaf(bf2f(qp[c * 8 + j]), bf2f(qp[64 + c * 8 + j]), p);
        p += __shfl_xor(p, 1); p += __shfl_xor(p, 2); p += __shfl_xor(p, 4);
        if (c == 0) qk_s[pos] = p;
    }

    float* co = ckv + (size_t)(bn * L + pos0) * 4096;
    const int kd0 = tid >> 4, vc = (tid & 15) * 4;
    #pragma unroll 2
    for (int pos = 0; pos < SBLK; ++pos) {
        const unsigned short* ks = &qkv_s[pos * NQKV + 64];
        const unsigned short* vs = &qkv_s[pos * NQKV + 128];
        unsigned short vb[4];
        *(uint2*)vb = *(const uint2*)&vs[vc];
        float v0 = bf2f(vb[0]), v1 = bf2f(vb[1]),
              v2 = bf2f(vb[2]), v3 = bf2f(vb[3]);
        #pragma unroll
        for (int j = 0; j < 4; ++j) {
            float kk = bf2f(ks[kd0 + j * 16]);
            f32x4 r;
            r.x = fmaf(decay, p4[j].x, kk * v0);
            r.y = fmaf(decay, p4[j].y, kk * v1);
            r.z = fmaf(decay, p4[j].z, kk * v2);
            r.w = fmaf(decay, p4[j].w, kk * v3);
            __builtin_nontemporal_store(
                r, (f32x4*)&co[(size_t)pos * 4096 + (tid + j * 256) * 4]);
        }
    }
    __syncthreads();   // qk_s ready

    const int wave = tid >> 6, lane = tid & 63;
    float a0 = 0.0f, a1 = 0.0f;
    const unsigned short* q0 = &qkv_s[wave * NQKV];
    const unsigned short* q1 = &qkv_s[(wave + 4) * NQKV];
    for (int kd = 0; kd < 64; ++kd) {
        float pv = pkv[kd * 64 + lane];
        a0 = fmaf(bf2f(q0[kd]), pv, a0);
        a1 = fmaf(bf2f(q1[kd]), pv, a1);
    }
    float o0 = fmaf(decay, a0, qk_s[wave]     * bf2f(q0[128 + lane]));
    float o1 = fmaf(decay, a1, qk_s[wave + 4] * bf2f(q1[128 + lane]));
    out[(size_t)(bn * L + pos0 + wave) * D + lane]     = o0;
    out[(size_t)(bn * L + pos0 + wave + 4) * D + lane] = o1;

    float s1 = o0 + o1, s2 = o0 * o0 + o1 * o1;
    #pragma unroll
    for (int off = 32; off; off >>= 1) {
        s1 += __shfl_down(s1, off);
        s2 += __shfl_down(s2, off);
    }
    if (lane == 0) { red[wave * 2] = s1; red[wave * 2 + 1] = s2; }
    __syncthreads();
    if (tid == 0) {
        float a = 0.0f, b2 = 0.0f;
        #pragma unroll
        for (int w = 0; w < 4; ++w) { a += red[w * 2]; b2 += red[w * 2 + 1]; }
        partials[(size_t)blk * 2]     = a;
        partials[(size_t)blk * 2 + 1] = b2;
    }
}

// ---------------------------------------------------------------------------
// Kernel 3: normalize with fused (redundant per-block) group reduction.
// ---------------------------------------------------------------------------
__global__ __launch_bounds__(256) void normalize_kernel(
    float* __restrict__ out, const float* __restrict__ partials)
{
    const int tid = threadIdx.x;
    const int g   = blockIdx.x >> 6;            // 64 blocks per group
    __shared__ float sm[2];

    float s1 = 0.0f, s2 = 0.0f;
    if (tid < 64) {
        f32x4 p = *((const f32x4*)(partials + (size_t)g * 256) + tid);
        s1 = p.x + p.z;
        s2 = p.y + p.w;
        #pragma unroll
        for (int off = 32; off; off >>= 1) {
            s1 += __shfl_down(s1, off);
            s2 += __shfl_down(s2, off);
        }
        if (tid == 0) {
            const float cnt = (float)(L * D);
            float mean = s1 / cnt;
            float var  = s2 / cnt - mean * mean;
            sm[0] = mean;
            sm[1] = rsqrtf(var + EPS);
        }
    }
    __syncthreads();
    const float mean = sm[0], rstd = sm[1];

    int idx = blockIdx.x * 256 + tid;           // float4 index
    f32x4 v = *((const f32x4*)out + idx);
    v.x = (v.x - mean) * rstd; v.y = (v.y - mean) * rstd;
    v.z = (v.z - mean) * rstd; v.w = (v.w - mean) * rstd;
    __builtin_nontemporal_store(v, (f32x4*)out + idx);
}

// ---------------------------------------------------------------------------
extern "C" void kernel_launch(void* const* d_in, const int* in_sizes, int n_in,
                              void* d_out, int out_size, void* d_ws, size_t ws_size,
                              hipStream_t stream)
{
    const float* x       = (const float*)d_in[0];
    const float* past_kv = (const float*)d_in[1];
    const float* Wq      = (const float*)d_in[2];
    const float* bq      = (const float*)d_in[3];
    const float* Wk      = (const float*)d_in[4];
    const float* bk      = (const float*)d_in[5];
    const float* Wv      = (const float*)d_in[6];
    const float* bv      = (const float*)d_in[7];

    float* out = (float*)d_out;                    // [M*64]
    float* ckv = out + (size_t)M * 64;             // [M*4096]

    unsigned short* qkvb = (unsigned short*)d_ws;              // M*192 bf16
    float* partials = (float*)(qkvb + (size_t)M * NQKV);       // NSBLKS*2

    proj_mfma_kernel<<<M / 64, 512, 0, stream>>>(x, Wq, Wk, Wv, bq, bk, bv, qkvb);
    store_out_kernel<<<NSBLKS, 256, 0, stream>>>(qkvb, past_kv, out, ckv, partials);
    normalize_kernel<<<(M * 16) / 256, 256, 0, stream>>>(out, partials);
}

// Round 15
// 134.003 us; speedup vs baseline: 1.0245x; 1.0245x over previous
//
#include <hip/hip_runtime.h>

// Shapes: x[2,16,1024,512] f32, past_kv[2,16,64,64] f32, Wq/Wk/Wv[64,512], b*[64]
// Outputs (concat): out [2,16,1024,64] (group-normed), current_kv [2,16,1024,64,64]

constexpr int B  = 2;
constexpr int NH = 16;
constexpr int L  = 1024;
constexpr int E  = 512;
constexpr int D  = 64;
constexpr int M  = B * NH * L;     // 32768 rows
constexpr int NQKV = 192;
constexpr int SBLK = 8;            // positions per store block
constexpr int NSBLKS = M / SBLK;   // 4096
constexpr float EPS = 1e-5f;

using short8 = __attribute__((ext_vector_type(8))) short;
using f32x4  = __attribute__((ext_vector_type(4))) float;

__device__ __forceinline__ unsigned short f2bf(float f) {
    union { float f; unsigned int u; } x; x.f = f;
    unsigned int u = x.u;
    return (unsigned short)((u + 0x7fffu + ((u >> 16) & 1u)) >> 16);
}
__device__ __forceinline__ float bf2f(unsigned short h) {
    union { unsigned int u; float f; } x; x.u = ((unsigned int)h) << 16;
    return x.f;
}

// ---------------------------------------------------------------------------
// Kernel 1: QKV projection via bf16 MFMA -> bf16 qkv. BM=64, XCD-swizzled.
// W converted f32->bf16 on the fly during staging (no convw pre-pass).
// ---------------------------------------------------------------------------
__global__ __launch_bounds__(512) void proj_mfma_kernel(
    const float* __restrict__ x,
    const float* __restrict__ Wq, const float* __restrict__ Wk,
    const float* __restrict__ Wv,
    const float* __restrict__ bq, const float* __restrict__ bk,
    const float* __restrict__ bv,
    unsigned short* __restrict__ qkvb)   // [M,192] bf16
{
    constexpr int BM = 64, BK = 64, LDP = 72;
    __shared__ unsigned short Xs[BM][LDP];
    __shared__ unsigned short Ws[NQKV][LDP];
    __shared__ float bias_s[NQKV];

    const int tid  = threadIdx.x;
    // XCD swizzle: 512 blocks = 8 XCDs x 64; XCD k handles rows [k*4096,(k+1)*4096)
    const int blk  = (blockIdx.x & 7) * 64 + (blockIdx.x >> 3);
    const int row0 = blk * BM;
    if (tid < NQKV)
        bias_s[tid] = (tid < 64) ? bq[tid] : (tid < 128) ? bk[tid - 64] : bv[tid - 128];

    const int wid  = tid >> 6;
    const int lane = tid & 63;
    const int wr   = wid >> 2;            // 0..1 row half (32 rows)
    const int wc   = wid & 3;             // 0..3 col block (48 cols)
    const int l15  = lane & 15;
    const int lk   = (lane >> 4) * 8;

    // Per-thread W staging targets (j-invariant across the k loop)
    const float* wsrc[3];
    int wr8[3], wc8[3];
    #pragma unroll
    for (int j = 0; j < 3; ++j) {
        int c = tid + j * 512;            // chunk 0..1535
        int wrow = c >> 3;                // 0..191
        wsrc[j] = (wrow < 64) ? Wq : (wrow < 128) ? Wk : Wv;
        wr8[j]  = wrow & 63;
        wc8[j]  = (c & 7) * 8;
    }

    f32x4 acc[2][3] = {};

    for (int k0 = 0; k0 < E; k0 += BK) {
        float4 xa[2];
        #pragma unroll
        for (int j = 0; j < 2; ++j) {
            int f = tid + j * 512;
            xa[j] = *(const float4*)&x[(size_t)(row0 + (f >> 4)) * E + k0 + (f & 15) * 4];
        }
        float4 wa[3][2];
        #pragma unroll
        for (int j = 0; j < 3; ++j) {
            wa[j][0] = *(const float4*)&wsrc[j][(size_t)wr8[j] * E + k0 + wc8[j]];
            wa[j][1] = *(const float4*)&wsrc[j][(size_t)wr8[j] * E + k0 + wc8[j] + 4];
        }
        __syncthreads();   // previous tile fully consumed
        #pragma unroll
        for (int j = 0; j < 2; ++j) {
            int f = tid + j * 512;
            unsigned short t4[4] = {f2bf(xa[j].x), f2bf(xa[j].y),
                                    f2bf(xa[j].z), f2bf(xa[j].w)};
            *(uint2*)&Xs[f >> 4][(f & 15) * 4] = *(uint2*)t4;
        }
        #pragma unroll
        for (int j = 0; j < 3; ++j) {
            int c = tid + j * 512;
            unsigned short t8[8] = {
                f2bf(wa[j][0].x), f2bf(wa[j][0].y), f2bf(wa[j][0].z), f2bf(wa[j][0].w),
                f2bf(wa[j][1].x), f2bf(wa[j][1].y), f2bf(wa[j][1].z), f2bf(wa[j][1].w)};
            *(short8*)&Ws[c >> 3][(c & 7) * 8] = *(short8*)t8;
        }
        __syncthreads();

        #pragma unroll
        for (int kk = 0; kk < 2; ++kk) {
            short8 a[2], b[3];
            #pragma unroll
            for (int mi = 0; mi < 2; ++mi)
                a[mi] = *(const short8*)&Xs[wr * 32 + mi * 16 + l15][kk * 32 + lk];
            #pragma unroll
            for (int ni = 0; ni < 3; ++ni)
                b[ni] = *(const short8*)&Ws[wc * 48 + ni * 16 + l15][kk * 32 + lk];
            #pragma unroll
            for (int mi = 0; mi < 2; ++mi)
                #pragma unroll
                for (int ni = 0; ni < 3; ++ni)
                    acc[mi][ni] = __builtin_amdgcn_mfma_f32_16x16x32_bf16(
                        a[mi], b[ni], acc[mi][ni], 0, 0, 0);
        }
    }

    #pragma unroll
    for (int mi = 0; mi < 2; ++mi) {
        #pragma unroll
        for (int ni = 0; ni < 3; ++ni) {
            int col = wc * 48 + ni * 16 + l15;
            float bb = bias_s[col];
            #pragma unroll
            for (int j = 0; j < 4; ++j) {
                int row = wr * 32 + mi * 16 + (lane >> 4) * 4 + j;
                qkvb[(size_t)(row0 + row) * NQKV + col] = f2bf(acc[mi][ni][j] + bb);
            }
        }
    }
}

// ---------------------------------------------------------------------------
// Kernel 2: store + out. 4096 blocks x 256 threads, 3 KB LDS, XCD-swizzled.
// ---------------------------------------------------------------------------
__global__ __launch_bounds__(256) void store_out_kernel(
    const unsigned short* __restrict__ qkvb,  // [M,192] bf16
    const float* __restrict__ past_kv,        // [B*NH,64,64] f32
    float* __restrict__ out,                  // [M,64] (pre-norm)
    float* __restrict__ ckv,                  // [M,4096]
    float* __restrict__ partials)             // [NSBLKS,2]
{
    __shared__ unsigned short qkv_s[SBLK * NQKV];   // 3 KB
    __shared__ float qk_s[SBLK];
    __shared__ float red[8];

    // XCD swizzle: 4096 = 8 x 512; XCD k handles bns [4k, 4k+4)
    const int blk  = (blockIdx.x & 7) * 512 + (blockIdx.x >> 3);
    const int bn   = blk >> 7;             // 128 blocks per (b,n)
    const int pos0 = (blk & 127) * SBLK;
    const int h    = bn & (NH - 1);
    const int tid  = threadIdx.x;
    const float decay = 1.0f - exp2f(-5.0f - (float)h);

    const unsigned short* qrow = qkvb + (size_t)(bn * L + pos0) * NQKV;
    if (tid < 192) ((uint4*)qkv_s)[tid] = ((const uint4*)qrow)[tid];

    const float* pkv = past_kv + (size_t)bn * 4096;
    float4 p4[4];
    #pragma unroll
    for (int j = 0; j < 4; ++j)
        p4[j] = *(const float4*)&pkv[(tid + j * 256) * 4];
    __syncthreads();

    if (tid < 64) {
        int pos = tid >> 3, c = tid & 7;
        const unsigned short* qp = &qkv_s[pos * NQKV];
        float p = 0.0f;
        #pragma unroll
        for (int j = 0; j < 8; ++j)
            p = fmaf(bf2f(qp[c * 8 + j]), bf2f(qp[64 + c * 8 + j]), p);
        p += __shfl_xor(p, 1); p += __shfl_xor(p, 2); p += __shfl_xor(p, 4);
        if (c == 0) qk_s[pos] = p;
    }

    float* co = ckv + (size_t)(bn * L + pos0) * 4096;
    const int kd0 = tid >> 4, vc = (tid & 15) * 4;
    #pragma unroll 2
    for (int pos = 0; pos < SBLK; ++pos) {
        const unsigned short* ks = &qkv_s[pos * NQKV + 64];
        const unsigned short* vs = &qkv_s[pos * NQKV + 128];
        unsigned short vb[4];
        *(uint2*)vb = *(const uint2*)&vs[vc];
        float v0 = bf2f(vb[0]), v1 = bf2f(vb[1]),
              v2 = bf2f(vb[2]), v3 = bf2f(vb[3]);
        #pragma unroll
        for (int j = 0; j < 4; ++j) {
            float kk = bf2f(ks[kd0 + j * 16]);
            f32x4 r;
            r.x = fmaf(decay, p4[j].x, kk * v0);
            r.y = fmaf(decay, p4[j].y, kk * v1);
            r.z = fmaf(decay, p4[j].z, kk * v2);
            r.w = fmaf(decay, p4[j].w, kk * v3);
            __builtin_nontemporal_store(
                r, (f32x4*)&co[(size_t)pos * 4096 + (tid + j * 256) * 4]);
        }
    }
    __syncthreads();   // qk_s ready

    const int wave = tid >> 6, lane = tid & 63;
    float a0 = 0.0f, a1 = 0.0f;
    const unsigned short* q0 = &qkv_s[wave * NQKV];
    const unsigned short* q1 = &qkv_s[(wave + 4) * NQKV];
    for (int kd = 0; kd < 64; ++kd) {
        float pv = pkv[kd * 64 + lane];
        a0 = fmaf(bf2f(q0[kd]), pv, a0);
        a1 = fmaf(bf2f(q1[kd]), pv, a1);
    }
    float o0 = fmaf(decay, a0, qk_s[wave]     * bf2f(q0[128 + lane]));
    float o1 = fmaf(decay, a1, qk_s[wave + 4] * bf2f(q1[128 + lane]));
    out[(size_t)(bn * L + pos0 + wave) * D + lane]     = o0;
    out[(size_t)(bn * L + pos0 + wave + 4) * D + lane] = o1;

    float s1 = o0 + o1, s2 = o0 * o0 + o1 * o1;
    #pragma unroll
    for (int off = 32; off; off >>= 1) {
        s1 += __shfl_down(s1, off);
        s2 += __shfl_down(s2, off);
    }
    if (lane == 0) { red[wave * 2] = s1; red[wave * 2 + 1] = s2; }
    __syncthreads();
    if (tid == 0) {
        float a = 0.0f, b2 = 0.0f;
        #pragma unroll
        for (int w = 0; w < 4; ++w) { a += red[w * 2]; b2 += red[w * 2 + 1]; }
        partials[(size_t)blk * 2]     = a;
        partials[(size_t)blk * 2 + 1] = b2;
    }
}

// ---------------------------------------------------------------------------
// Kernel 3: normalize with fused (redundant per-block) group reduction.
// 2048 blocks x 256 threads; each block lies entirely within one group.
// ---------------------------------------------------------------------------
__global__ __launch_bounds__(256) void normalize_kernel(
    float* __restrict__ out, const float* __restrict__ partials)
{
    const int tid = threadIdx.x;
    const int g   = blockIdx.x >> 6;            // 64 blocks per group
    __shared__ float sm[2];

    // group g's partials: 128 blocks x (s1,s2) = 256 contiguous floats
    float s1 = 0.0f, s2 = 0.0f;
    if (tid < 64) {
        f32x4 p = *((const f32x4*)(partials + (size_t)g * 256) + tid);
        s1 = p.x + p.z;
        s2 = p.y + p.w;
        #pragma unroll
        for (int off = 32; off; off >>= 1) {
            s1 += __shfl_down(s1, off);
            s2 += __shfl_down(s2, off);
        }
        if (tid == 0) {
            const float cnt = (float)(L * D);
            float mean = s1 / cnt;
            float var  = s2 / cnt - mean * mean;
            sm[0] = mean;
            sm[1] = rsqrtf(var + EPS);
        }
    }
    __syncthreads();
    const float mean = sm[0], rstd = sm[1];

    int idx = blockIdx.x * 256 + tid;           // float4 index
    f32x4 v = *((const f32x4*)out + idx);
    v.x = (v.x - mean) * rstd; v.y = (v.y - mean) * rstd;
    v.z = (v.z - mean) * rstd; v.w = (v.w - mean) * rstd;
    __builtin_nontemporal_store(v, (f32x4*)out + idx);
}

// ---------------------------------------------------------------------------
extern "C" void kernel_launch(void* const* d_in, const int* in_sizes, int n_in,
                              void* d_out, int out_size, void* d_ws, size_t ws_size,
                              hipStream_t stream)
{
    const float* x       = (const float*)d_in[0];
    const float* past_kv = (const float*)d_in[1];
    const float* Wq      = (const float*)d_in[2];
    const float* bq      = (const float*)d_in[3];
    const float* Wk      = (const float*)d_in[4];
    const float* bk      = (const float*)d_in[5];
    const float* Wv      = (const float*)d_in[6];
    const float* bv      = (const float*)d_in[7];

    float* out = (float*)d_out;                    // [M*64]
    float* ckv = out + (size_t)M * 64;             // [M*4096]

    unsigned short* qkvb = (unsigned short*)d_ws;              // M*192 bf16
    float* partials = (float*)(qkvb + (size_t)M * NQKV);       // NSBLKS*2

    proj_mfma_kernel<<<M / 64, 512, 0, stream>>>(x, Wq, Wk, Wv, bq, bk, bv, qkvb);
    store_out_kernel<<<NSBLKS, 256, 0, stream>>>(qkvb, past_kv, out, ckv, partials);
    normalize_kernel<<<(M * 16) / 256, 256, 0, stream>>>(out, partials);
}